// Round 4
// baseline (887.294 us; speedup 1.0000x reference)
//
#include <hip/hip_runtime.h>
#include <hip/hip_bf16.h>

using f32x4  = __attribute__((ext_vector_type(4))) float;
using bf16x8 = __attribute__((ext_vector_type(8))) short;

#define KD 128
#define NBH 2048      // hist blocks inside mega1
#define NPART 8       // scatter partitions (== XCDs)
#define SCAT_BPP 160  // scatter blocks per partition

__device__ inline float wred_sum(float v){
#pragma unroll
  for (int o = 32; o > 0; o >>= 1) v += __shfl_xor(v, o, 64);
  return v;
}
__device__ inline float wred_max(float v){
#pragma unroll
  for (int o = 32; o > 0; o >>= 1) v = fmaxf(v, __shfl_xor(v, o, 64));
  return v;
}
__device__ inline float bf2f(short s){
  return __uint_as_float(((unsigned int)(unsigned short)s) << 16);
}

// ---------------- weight convert: 4x [128][128] f32 -> bf16 ----------------
__global__ __launch_bounds__(256) void k_cvt_w(const float* __restrict__ w0,
                                               const float* __restrict__ w1,
                                               const float* __restrict__ w2,
                                               const float* __restrict__ w3,
                                               short* __restrict__ out){
  int i = blockIdx.x * 256 + threadIdx.x;            // 0..65535
  const float* src = (i < 16384) ? w0 : (i < 32768) ? w1 : (i < 49152) ? w2 : w3;
  float v = src[i & 16383];
  __hip_bfloat16 b = __float2bfloat16(v);
  out[i] = __builtin_bit_cast(short, b);
}

// ---------------- GEMM body: z = h @ W^T  (+ es = z . attn[:128]) ----------------
__device__ void gemm_body(const float* __restrict__ A0, int nA,
                          const float* __restrict__ A1,
                          const short* __restrict__ Wb, const float* __restrict__ attn,
                          __hip_bfloat16* __restrict__ Z, float* __restrict__ es,
                          int zbase, int nrows, int blk)
{
  const int wave = threadIdx.x >> 6, lane = threadIdx.x & 63;
  const int lr = lane & 15, lk = lane >> 4;
  const int row0 = blk * 64 + wave * 16;

  bf16x8 afrag[4];
  {
    int r = row0 + lr;
    bool rv = (r < nrows);
    int node = zbase + r;
    const float* ap = A0;
    if (rv) ap = (node < nA) ? (A0 + (size_t)node * KD) : (A1 + (size_t)(node - nA) * KD);
#pragma unroll
    for (int t = 0; t < 4; ++t){
      float x[8];
      if (rv){
        float4 u0 = *(const float4*)(ap + t * 32 + lk * 8);
        float4 u1 = *(const float4*)(ap + t * 32 + lk * 8 + 4);
        x[0]=u0.x; x[1]=u0.y; x[2]=u0.z; x[3]=u0.w;
        x[4]=u1.x; x[5]=u1.y; x[6]=u1.z; x[7]=u1.w;
      } else {
#pragma unroll
        for (int j = 0; j < 8; ++j) x[j] = 0.f;
      }
      bf16x8 af;
#pragma unroll
      for (int j = 0; j < 8; ++j){
        __hip_bfloat16 b = __float2bfloat16(x[j]);
        af[j] = __builtin_bit_cast(short, b);
      }
      afrag[t] = af;
    }
  }

  f32x4 acc[8];
#pragma unroll
  for (int c = 0; c < 8; ++c){ acc[c][0]=0.f; acc[c][1]=0.f; acc[c][2]=0.f; acc[c][3]=0.f; }

#pragma unroll
  for (int c = 0; c < 8; ++c){
#pragma unroll
    for (int t = 0; t < 4; ++t){
      bf16x8 bf = *(const bf16x8*)(Wb + (c * 16 + lr) * KD + t * 32 + lk * 8);
      acc[c] = __builtin_amdgcn_mfma_f32_16x16x32_bf16(afrag[t], bf, acc[c], 0, 0, 0);
    }
  }

  float p[4] = {0.f, 0.f, 0.f, 0.f};
#pragma unroll
  for (int c = 0; c < 8; ++c){
    float av = attn[c * 16 + lr];
#pragma unroll
    for (int q = 0; q < 4; ++q){
      int r = row0 + lk * 4 + q;
      if (r < nrows) Z[(size_t)r * KD + c * 16 + lr] = __float2bfloat16(acc[c][q]);
      p[q] += acc[c][q] * av;
    }
  }
#pragma unroll
  for (int q = 0; q < 4; ++q){
#pragma unroll
    for (int o = 1; o < 16; o <<= 1) p[q] += __shfl_xor(p[q], o, 64);
  }
  if (lr == 0){
#pragma unroll
    for (int q = 0; q < 4; ++q){
      int r = row0 + lk * 4 + q;
      if (r < nrows) es[r] = p[q];
    }
  }
}

// ---------------- mega1: hist blocks (latency-bound) + gemm blocks ----------------
struct GJob { const float* A1; const float* attn; __hip_bfloat16* Z; float* es;
              int zbase, nrows, blk0, wboff; };
struct Mega1Args {
  const int* d0; const int* d1; const int* d2; const int* d3;
  int nse, nek, rebase23;
  int* cnt;
  const float* A0; int nA;
  const short* Wb;
  GJob j[4];
};

__global__ __launch_bounds__(256) void k_mega1(Mega1Args a){
  int b = blockIdx.x;
  if (b < NBH){
    long total = 2L * a.nse + 2L * a.nek;
    for (long i = (long)b * 256 + threadIdx.x; i < total; i += (long)NBH * 256){
      long k = i; const int* dp; int rb;
      if (k < a.nse){ dp = a.d0; rb = 0; }
      else if ((k -= a.nse) < a.nse){ dp = a.d1; rb = 0; }
      else if ((k -= a.nse) < a.nek){ dp = a.d2; rb = a.rebase23; }
      else { k -= a.nek; dp = a.d3; rb = a.rebase23; }
      atomicAdd(&a.cnt[dp[k] + rb], 1);
    }
  } else {
    int gb = b - NBH;
    int ji = 3;
    if (gb < a.j[1].blk0) ji = 0;
    else if (gb < a.j[2].blk0) ji = 1;
    else if (gb < a.j[3].blk0) ji = 2;
    GJob J = a.j[ji];
    gemm_body(a.A0, a.nA, J.A1, a.Wb + J.wboff, J.attn, J.Z, J.es,
              J.zbase, J.nrows, gb - J.blk0);
  }
}

// ---------------- scan ----------------
__global__ __launch_bounds__(1024) void k_scan1(const int* __restrict__ cnt, int n,
                                                int* __restrict__ offs, int* __restrict__ bsum){
  __shared__ int sh[1024];
  int tid = threadIdx.x;
  int i = blockIdx.x * 1024 + tid;
  int v = (i < n) ? cnt[i] : 0;
  sh[tid] = v; __syncthreads();
  for (int o = 1; o < 1024; o <<= 1){
    int u = (tid >= o) ? sh[tid - o] : 0;
    __syncthreads();
    sh[tid] += u;
    __syncthreads();
  }
  if (i < n) offs[i + 1] = sh[tid];
  if (tid == 1023) bsum[blockIdx.x] = sh[tid];
}
__global__ __launch_bounds__(1024) void k_scan2(int* __restrict__ bsum, int nb){
  __shared__ int sh[1024];
  int tid = threadIdx.x;
  int v = (tid < nb) ? bsum[tid] : 0;
  sh[tid] = v; __syncthreads();
  for (int o = 1; o < 1024; o <<= 1){
    int u = (tid >= o) ? sh[tid - o] : 0;
    __syncthreads();
    sh[tid] += u;
    __syncthreads();
  }
  if (tid < nb) bsum[tid] = sh[tid] - v;   // exclusive
}
__global__ __launch_bounds__(1024) void k_scan3(const int* __restrict__ cnt, int n,
                                                int* __restrict__ offs,
                                                const int* __restrict__ bsum,
                                                int* __restrict__ cursor){
  int i = blockIdx.x * 1024 + threadIdx.x;
  if (i < n){
    int incl = offs[i + 1] + bsum[i >> 10];
    offs[i + 1] = incl;
    cursor[i] = incl - cnt[i];
    if (i == 0) offs[0] = 0;
  }
}

// ---------------- partition bounds: 8 edge-balanced seg ranges ----------------
__global__ void k_pbound(const int* __restrict__ offs, int nseg, long tote,
                         int* __restrict__ pb){
  int p = threadIdx.x;          // 0..NPART
  if (p > NPART) return;
  if (p == 0){ pb[0] = 0; return; }
  if (p == NPART){ pb[NPART] = nseg; return; }
  long target = (tote * p) / NPART;
  int lo = 0, hi = nseg;        // smallest seg with offs[seg] >= target
  while (lo < hi){
    int mid = (lo + hi) >> 1;
    if ((long)offs[mid] >= target) hi = mid; else lo = mid + 1;
  }
  pb[p] = lo;
}

// ---------------- scatter: XCD-partitioned by dst-segment range ----------------
struct ScatArgs {
  const int* s0; const int* d0; const int* s1; const int* d1;
  const int* s2; const int* d2; const int* s3; const int* d3;
  const float* e0; const float* e1; const float* e2; const float* e3;
  int nse, nek, S, E;
  int* cursor; int2* edges;
  const int* pb;
};
__device__ inline void scat_stream(const int* __restrict__ sp, const int* __restrict__ dp,
                                   const float* __restrict__ ep, int n, int rb, int zb,
                                   int lo, int hi, int bb,
                                   int* __restrict__ cursor, int2* __restrict__ edges){
  for (int i = bb * 256 + (int)threadIdx.x; i < n; i += SCAT_BPP * 256){
    int d = dp[i] + rb;
    if (d >= lo && d < hi){
      int s = sp[i];
      float ev = ep[s - zb];
      int pos = atomicAdd(&cursor[d], 1);
      edges[pos] = make_int2(s, __float_as_int(ev));
    }
  }
}
__global__ __launch_bounds__(256) void k_scat(ScatArgs a){
  const int p  = blockIdx.x & (NPART - 1);   // partition == XCD (round-robin dispatch)
  const int bb = blockIdx.x >> 3;
  const int lo = a.pb[p], hi = a.pb[p + 1];
  scat_stream(a.s0, a.d0, a.e0, a.nse, 0,         a.S, lo, hi, bb, a.cursor, a.edges);
  scat_stream(a.s1, a.d1, a.e1, a.nse, 0,         0,   lo, hi, bb, a.cursor, a.edges);
  scat_stream(a.s2, a.d2, a.e2, a.nek, a.S + a.E, a.E, lo, hi, bb, a.cursor, a.edges);
  scat_stream(a.s3, a.d3, a.e3, a.nek, a.S + a.E, 0,   lo, hi, bb, a.cursor, a.edges);
}

// ---------------- per-dst-segment softmax + weighted aggregation ----------------
template<int NWAVES, int MODE>
__global__ __launch_bounds__(NWAVES * 64) void k_agg(
    const int* __restrict__ offs, int segbase,
    const int2* __restrict__ edges,
    const __hip_bfloat16* __restrict__ Z, int zbase,
    const float* __restrict__ emb, float* __restrict__ out,
    const float* __restrict__ efk_buf,
    const float* __restrict__ attn0, const float* __restrict__ b0p,
    const float* __restrict__ attn1, const float* __restrict__ b1p)
{
  constexpr int NT = NWAVES * 64;
  constexpr int NSLOT = NWAVES * 4;
  __shared__ float sred[NWAVES];
  __shared__ float lacc[NWAVES][KD];
  const int tid = threadIdx.x;
  const int wave = tid >> 6, lane = tid & 63;
  const int sub = lane >> 4, li = lane & 15;
  const int seg = segbase + blockIdx.x;
  const int beg = offs[seg], end = offs[seg + 1];

  float m = -3.0e38f;
  for (int i = beg + tid; i < end; i += NT) m = fmaxf(m, __int_as_float(edges[i].y));
  m = wred_max(m);
  if (lane == 0) sred[wave] = m;
  __syncthreads();
  float mm = sred[0];
#pragma unroll
  for (int i = 1; i < NWAVES; ++i) mm = fmaxf(mm, sred[i]);
  __syncthreads();

  float ds = 0.f;
  for (int i = beg + tid; i < end; i += NT) ds += __expf(__int_as_float(edges[i].y) - mm);
  ds = wred_sum(ds);
  if (lane == 0) sred[wave] = ds;
  __syncthreads();
  float dsum = 0.f;
#pragma unroll
  for (int i = 0; i < NWAVES; ++i) dsum += sred[i];
  float rden = (end > beg) ? 1.f / dsum : 0.f;

  float acc[8];
#pragma unroll
  for (int j = 0; j < 8; ++j) acc[j] = 0.f;
  const int slot = wave * 4 + sub;
  for (int i = beg + slot; i < end; i += NSLOT){
    int2 ed = edges[i];
    float w = __expf(__int_as_float(ed.y) - mm);
    bf16x8 z = *(const bf16x8*)(Z + (size_t)(ed.x - zbase) * KD + li * 8);
#pragma unroll
    for (int j = 0; j < 8; ++j) acc[j] = fmaf(w, bf2f(z[j]), acc[j]);
  }
#pragma unroll
  for (int j = 0; j < 8; ++j){
    acc[j] += __shfl_xor(acc[j], 16, 64);
    acc[j] += __shfl_xor(acc[j], 32, 64);
  }
  __syncthreads();
  if (sub == 0){
    f32x4 v0, v1;
#pragma unroll
    for (int j = 0; j < 4; ++j){ v0[j] = acc[j]; v1[j] = acc[4 + j]; }
    *(f32x4*)&lacc[wave][li * 8]     = v0;
    *(f32x4*)&lacc[wave][li * 8 + 4] = v1;
  }
  __syncthreads();

  float accw = 0.f, ex = 0.f, ek = 0.f;
  if (tid < KD){
    float a = 0.f;
#pragma unroll
    for (int wv = 0; wv < NWAVES; ++wv) a += lacc[wv][tid];
    accw = a * rden;
    if (MODE == 1) ex = emb[(size_t)blockIdx.x * KD + tid];
    if (MODE == 2){
      ex = emb[(size_t)blockIdx.x * KD + tid];
      ek = efk_buf[(size_t)blockIdx.x * KD + tid];
    }
  }

  if (MODE == 0){
    if (tid < KD) out[(size_t)blockIdx.x * KD + tid] = accw;
  } else if (MODE == 1){
    if (tid < KD) out[(size_t)blockIdx.x * KD + tid] = ex + accw;
  } else {
    float q0 = 0.f, q1 = 0.f;
    if (tid < KD){
      q0 = ex * attn0[tid] + accw * attn0[KD + tid];
      q1 = ex * attn1[tid] + ek * attn1[KD + tid];
    }
    q0 = wred_sum(q0); q1 = wred_sum(q1);
    if (lane == 0) sred[wave] = q0;
    __syncthreads();
    float s0 = 0.f;
#pragma unroll
    for (int i = 0; i < NWAVES; ++i) s0 += sred[i];
    __syncthreads();
    if (lane == 0) sred[wave] = q1;
    __syncthreads();
    float s1 = 0.f;
#pragma unroll
    for (int i = 0; i < NWAVES; ++i) s1 += sred[i];
    float sc0 = s0 + b0p[0], sc1 = s1 + b1p[0];
    float mx = fmaxf(sc0, sc1);
    float w0 = __expf(sc0 - mx), w1 = __expf(sc1 - mx);
    float inv = 1.f / (w0 + w1);
    w0 *= inv; w1 *= inv;
    if (tid < KD) out[(size_t)blockIdx.x * KD + tid] = ex + w0 * accw + w1 * ek;
  }
}

extern "C" void kernel_launch(void* const* d_in, const int* in_sizes, int n_in,
                              void* d_out, int out_size, void* d_ws, size_t ws_size,
                              hipStream_t stream){
  const int S  = in_sizes[0] / KD;     // 40000
  const int E  = in_sizes[1] / KD;     // 18000
  const int KN = in_sizes[2] / KD;     // 128
  const int nse = in_sizes[19];        // 1.5M
  const int nek = in_sizes[23];        // 180K

  const float* stu  = (const float*)d_in[0];
  const float* exer = (const float*)d_in[1];
  const float* kn   = (const float*)d_in[2];
  const float* sfe_fcW = (const float*)d_in[3];  const float* sfe_attn = (const float*)d_in[4];
  const float* efs_fcW = (const float*)d_in[5];  const float* efs_attn = (const float*)d_in[6];
  const float* efk_fcW = (const float*)d_in[7];  const float* efk_attn = (const float*)d_in[8];
  const float* kfe_fcW = (const float*)d_in[9];  const float* kfe_attn = (const float*)d_in[10];
  const float* ea0W = (const float*)d_in[13]; const float* ea0b = (const float*)d_in[14];
  const float* ea1W = (const float*)d_in[15]; const float* ea1b = (const float*)d_in[16];
  const int* sfe_src = (const int*)d_in[19]; const int* sfe_dst = (const int*)d_in[20];
  const int* efs_src = (const int*)d_in[21]; const int* efs_dst = (const int*)d_in[22];
  const int* efk_src = (const int*)d_in[23]; const int* efk_dst = (const int*)d_in[24];
  const int* kfe_src = (const int*)d_in[25]; const int* kfe_dst = (const int*)d_in[26];
  float* out = (float*)d_out;

  // ---- workspace carve-up ----
  char* w = (char*)d_ws;
  auto alloc = [&](size_t bytes) -> char* {
    char* p = w; w += (bytes + 255) & ~(size_t)255; return p;
  };
  short* Wb               = (short*)alloc((size_t)4 * 16384 * 2);
  __hip_bfloat16* z_sfe   = (__hip_bfloat16*)alloc((size_t)E  * KD * 2);
  __hip_bfloat16* z_efs   = (__hip_bfloat16*)alloc((size_t)S  * KD * 2);
  __hip_bfloat16* z_efk   = (__hip_bfloat16*)alloc((size_t)KN * KD * 2);
  __hip_bfloat16* z_kfe   = (__hip_bfloat16*)alloc((size_t)E  * KD * 2);
  float* es_sfe = (float*)alloc((size_t)E  * 4);
  float* es_efs = (float*)alloc((size_t)S  * 4);
  float* es_efk = (float*)alloc((size_t)KN * 4);
  float* es_kfe = (float*)alloc((size_t)E  * 4);
  float* efk_buf = (float*)alloc((size_t)E * KD * 4);
  const int NSEG = S + E + E + KN;     // 76128
  int* cnt    = (int*)alloc((size_t)NSEG * 4);
  int* offs   = (int*)alloc((size_t)(NSEG + 1) * 4);
  int* cursor = (int*)alloc((size_t)NSEG * 4);
  int* bsum   = (int*)alloc(1024 * 4);
  int* pb     = (int*)alloc((NPART + 1) * 4);
  const size_t TOTE = 2 * (size_t)nse + 2 * (size_t)nek;
  int2* edges = (int2*)alloc(TOTE * 8);

  hipMemsetAsync(cnt, 0, (size_t)NSEG * 4, stream);

  k_cvt_w<<<256, 256, 0, stream>>>(sfe_fcW, efs_fcW, efk_fcW, kfe_fcW, Wb);

  // mega1: hist (2048 blocks) + 4 gemm jobs
  const int nbE = (E + 63) / 64, nbS = (S + 63) / 64, nbK = (KN + 63) / 64;
  Mega1Args ma;
  ma.d0 = sfe_dst; ma.d1 = efs_dst; ma.d2 = efk_dst; ma.d3 = kfe_dst;
  ma.nse = nse; ma.nek = nek; ma.rebase23 = S + E; ma.cnt = cnt;
  ma.A0 = exer; ma.nA = E; ma.Wb = Wb;
  ma.j[0] = { stu, sfe_attn, z_sfe, es_sfe, S, E,  0,                 0 };
  ma.j[1] = { stu, efs_attn, z_efs, es_efs, 0, S,  nbE,               16384 };
  ma.j[2] = { kn,  efk_attn, z_efk, es_efk, E, KN, nbE + nbS,         32768 };
  ma.j[3] = { kn,  kfe_attn, z_kfe, es_kfe, 0, E,  nbE + nbS + nbK,   49152 };
  const int NBG = nbE + nbS + nbK + nbE;
  k_mega1<<<NBH + NBG, 256, 0, stream>>>(ma);

  int nb = (NSEG + 1023) / 1024;
  k_scan1<<<nb, 1024, 0, stream>>>(cnt, NSEG, offs, bsum);
  k_scan2<<<1, 1024, 0, stream>>>(bsum, nb);
  k_scan3<<<nb, 1024, 0, stream>>>(cnt, NSEG, offs, bsum, cursor);
  k_pbound<<<1, NPART + 1, 0, stream>>>(offs, NSEG, (long)TOTE, pb);

  ScatArgs sa;
  sa.s0 = sfe_src; sa.d0 = sfe_dst; sa.s1 = efs_src; sa.d1 = efs_dst;
  sa.s2 = efk_src; sa.d2 = efk_dst; sa.s3 = kfe_src; sa.d3 = kfe_dst;
  sa.e0 = es_sfe; sa.e1 = es_efs; sa.e2 = es_efk; sa.e3 = es_kfe;
  sa.nse = nse; sa.nek = nek; sa.S = S; sa.E = E;
  sa.cursor = cursor; sa.edges = edges;
  sa.pb = pb;
  k_scat<<<NPART * SCAT_BPP, 256, 0, stream>>>(sa);

  // aggregations (efk first: its buffer feeds the exercise combine)
  k_agg<2, 0><<<E, 128, 0, stream>>>(offs, S + E,     edges, z_efk, E, nullptr, efk_buf,
                                     nullptr, nullptr, nullptr, nullptr, nullptr);
  k_agg<4, 1><<<S, 256, 0, stream>>>(offs, 0,         edges, z_sfe, S, stu, out,
                                     nullptr, nullptr, nullptr, nullptr, nullptr);
  k_agg<16, 1><<<KN, 1024, 0, stream>>>(offs, S + 2 * E, edges, z_kfe, 0, kn,
                                        out + (size_t)(S + E) * KD,
                                        nullptr, nullptr, nullptr, nullptr, nullptr);
  k_agg<4, 2><<<E, 256, 0, stream>>>(offs, S,         edges, z_efs, 0, exer,
                                     out + (size_t)S * KD,
                                     efk_buf, ea0W, ea0b, ea1W, ea1b);
}

// Round 5
// 778.802 us; speedup vs baseline: 1.1393x; 1.1393x over previous
//
#include <hip/hip_runtime.h>
#include <hip/hip_bf16.h>

using f32x4  = __attribute__((ext_vector_type(4))) float;
using bf16x8 = __attribute__((ext_vector_type(8))) short;

#define KD 128
#define NBH 2048      // hist blocks inside mega1
#define NPART 8       // partitions (== XCDs)
#define SCAT_BPP 160  // scatter blocks per partition

__device__ inline float wred_sum(float v){
#pragma unroll
  for (int o = 32; o > 0; o >>= 1) v += __shfl_xor(v, o, 64);
  return v;
}
__device__ inline float wred_max(float v){
#pragma unroll
  for (int o = 32; o > 0; o >>= 1) v = fmaxf(v, __shfl_xor(v, o, 64));
  return v;
}
__device__ inline float bf2f(short s){
  return __uint_as_float(((unsigned int)(unsigned short)s) << 16);
}

// ---------------- weight convert: 4x [128][128] f32 -> bf16 ----------------
__global__ __launch_bounds__(256) void k_cvt_w(const float* __restrict__ w0,
                                               const float* __restrict__ w1,
                                               const float* __restrict__ w2,
                                               const float* __restrict__ w3,
                                               short* __restrict__ out){
  int i = blockIdx.x * 256 + threadIdx.x;            // 0..65535
  const float* src = (i < 16384) ? w0 : (i < 32768) ? w1 : (i < 49152) ? w2 : w3;
  float v = src[i & 16383];
  __hip_bfloat16 b = __float2bfloat16(v);
  out[i] = __builtin_bit_cast(short, b);
}

// ---------------- GEMM body: z = h @ W^T  (+ es = z . attn[:128]) ----------------
__device__ void gemm_body(const float* __restrict__ A0, int nA,
                          const float* __restrict__ A1,
                          const short* __restrict__ Wb, const float* __restrict__ attn,
                          __hip_bfloat16* __restrict__ Z, float* __restrict__ es,
                          int zbase, int nrows, int blk)
{
  const int wave = threadIdx.x >> 6, lane = threadIdx.x & 63;
  const int lr = lane & 15, lk = lane >> 4;
  const int row0 = blk * 64 + wave * 16;

  bf16x8 afrag[4];
  {
    int r = row0 + lr;
    bool rv = (r < nrows);
    int node = zbase + r;
    const float* ap = A0;
    if (rv) ap = (node < nA) ? (A0 + (size_t)node * KD) : (A1 + (size_t)(node - nA) * KD);
#pragma unroll
    for (int t = 0; t < 4; ++t){
      float x[8];
      if (rv){
        float4 u0 = *(const float4*)(ap + t * 32 + lk * 8);
        float4 u1 = *(const float4*)(ap + t * 32 + lk * 8 + 4);
        x[0]=u0.x; x[1]=u0.y; x[2]=u0.z; x[3]=u0.w;
        x[4]=u1.x; x[5]=u1.y; x[6]=u1.z; x[7]=u1.w;
      } else {
#pragma unroll
        for (int j = 0; j < 8; ++j) x[j] = 0.f;
      }
      bf16x8 af;
#pragma unroll
      for (int j = 0; j < 8; ++j){
        __hip_bfloat16 b = __float2bfloat16(x[j]);
        af[j] = __builtin_bit_cast(short, b);
      }
      afrag[t] = af;
    }
  }

  f32x4 acc[8];
#pragma unroll
  for (int c = 0; c < 8; ++c){ acc[c][0]=0.f; acc[c][1]=0.f; acc[c][2]=0.f; acc[c][3]=0.f; }

#pragma unroll
  for (int c = 0; c < 8; ++c){
#pragma unroll
    for (int t = 0; t < 4; ++t){
      bf16x8 bf = *(const bf16x8*)(Wb + (c * 16 + lr) * KD + t * 32 + lk * 8);
      acc[c] = __builtin_amdgcn_mfma_f32_16x16x32_bf16(afrag[t], bf, acc[c], 0, 0, 0);
    }
  }

  float p[4] = {0.f, 0.f, 0.f, 0.f};
#pragma unroll
  for (int c = 0; c < 8; ++c){
    float av = attn[c * 16 + lr];
#pragma unroll
    for (int q = 0; q < 4; ++q){
      int r = row0 + lk * 4 + q;
      if (r < nrows) Z[(size_t)r * KD + c * 16 + lr] = __float2bfloat16(acc[c][q]);
      p[q] += acc[c][q] * av;
    }
  }
#pragma unroll
  for (int q = 0; q < 4; ++q){
#pragma unroll
    for (int o = 1; o < 16; o <<= 1) p[q] += __shfl_xor(p[q], o, 64);
  }
  if (lr == 0){
#pragma unroll
    for (int q = 0; q < 4; ++q){
      int r = row0 + lk * 4 + q;
      if (r < nrows) es[r] = p[q];
    }
  }
}

// ---------------- mega1: hist blocks (per-XCD privatized) + gemm blocks ----------------
struct GJob { const float* A1; const float* attn; __hip_bfloat16* Z; float* es;
              int zbase, nrows, blk0, wboff; };
struct Mega1Args {
  const int* d0; const int* d1; const int* d2; const int* d3;
  int nse, nek, rebase23, nseg;
  int* cnt8;                       // [NPART][nseg]
  const float* A0; int nA;
  const short* Wb;
  GJob j[4];
};

__global__ __launch_bounds__(256) void k_mega1(Mega1Args a){
  int b = blockIdx.x;
  if (b < NBH){
    // per-XCD private histogram copy: blocks dispatch round-robin over XCDs,
    // so copy (b&7) stays in one XCD's L2 -> no cross-XCD line ping-pong.
    int* cnt = a.cnt8 + (size_t)(b & (NPART - 1)) * a.nseg;
    long total = 2L * a.nse + 2L * a.nek;
    for (long i = (long)b * 256 + threadIdx.x; i < total; i += (long)NBH * 256){
      long k = i; const int* dp; int rb;
      if (k < a.nse){ dp = a.d0; rb = 0; }
      else if ((k -= a.nse) < a.nse){ dp = a.d1; rb = 0; }
      else if ((k -= a.nse) < a.nek){ dp = a.d2; rb = a.rebase23; }
      else { k -= a.nek; dp = a.d3; rb = a.rebase23; }
      atomicAdd(&cnt[dp[k] + rb], 1);
    }
  } else {
    int gb = b - NBH;
    int ji = 3;
    if (gb < a.j[1].blk0) ji = 0;
    else if (gb < a.j[2].blk0) ji = 1;
    else if (gb < a.j[3].blk0) ji = 2;
    GJob J = a.j[ji];
    gemm_body(a.A0, a.nA, J.A1, a.Wb + J.wboff, J.attn, J.Z, J.es,
              J.zbase, J.nrows, gb - J.blk0);
  }
}

// ---------------- scan (scan1 merges the 8 private histograms) ----------------
__global__ __launch_bounds__(1024) void k_scan1(const int* __restrict__ cnt8,
                                                int* __restrict__ cnt, int n,
                                                int* __restrict__ offs, int* __restrict__ bsum){
  __shared__ int sh[1024];
  int tid = threadIdx.x;
  int i = blockIdx.x * 1024 + tid;
  int v = 0;
  if (i < n){
#pragma unroll
    for (int p = 0; p < NPART; ++p) v += cnt8[(size_t)p * n + i];
    cnt[i] = v;
  }
  sh[tid] = v; __syncthreads();
  for (int o = 1; o < 1024; o <<= 1){
    int u = (tid >= o) ? sh[tid - o] : 0;
    __syncthreads();
    sh[tid] += u;
    __syncthreads();
  }
  if (i < n) offs[i + 1] = sh[tid];
  if (tid == 1023) bsum[blockIdx.x] = sh[tid];
}
__global__ __launch_bounds__(1024) void k_scan2(int* __restrict__ bsum, int nb){
  __shared__ int sh[1024];
  int tid = threadIdx.x;
  int v = (tid < nb) ? bsum[tid] : 0;
  sh[tid] = v; __syncthreads();
  for (int o = 1; o < 1024; o <<= 1){
    int u = (tid >= o) ? sh[tid - o] : 0;
    __syncthreads();
    sh[tid] += u;
    __syncthreads();
  }
  if (tid < nb) bsum[tid] = sh[tid] - v;   // exclusive
}
__global__ __launch_bounds__(1024) void k_scan3(const int* __restrict__ cnt, int n,
                                                int* __restrict__ offs,
                                                const int* __restrict__ bsum,
                                                int* __restrict__ cursor){
  int i = blockIdx.x * 1024 + threadIdx.x;
  if (i < n){
    int incl = offs[i + 1] + bsum[i >> 10];
    offs[i + 1] = incl;
    cursor[i] = incl - cnt[i];
    if (i == 0) offs[0] = 0;
  }
}

// ---------------- partition bounds: 8 edge-balanced seg ranges ----------------
__global__ void k_pbound(const int* __restrict__ offs, int nseg, long tote,
                         int* __restrict__ pb){
  int p = threadIdx.x;          // 0..NPART
  if (p > NPART) return;
  if (p == 0){ pb[0] = 0; return; }
  if (p == NPART){ pb[NPART] = nseg; return; }
  long target = (tote * p) / NPART;
  int lo = 0, hi = nseg;        // smallest seg with offs[seg] >= target
  while (lo < hi){
    int mid = (lo + hi) >> 1;
    if ((long)offs[mid] >= target) hi = mid; else lo = mid + 1;
  }
  pb[p] = lo;
}

// ---------------- scatter: XCD-partitioned by dst-segment range ----------------
struct ScatArgs {
  const int* s0; const int* d0; const int* s1; const int* d1;
  const int* s2; const int* d2; const int* s3; const int* d3;
  const float* e0; const float* e1; const float* e2; const float* e3;
  int nse, nek, S, E;
  int* cursor; int2* edges;
  const int* pb;
};
__device__ inline void scat_stream(const int* __restrict__ sp, const int* __restrict__ dp,
                                   const float* __restrict__ ep, int n, int rb, int zb,
                                   int lo, int hi, int bb,
                                   int* __restrict__ cursor, int2* __restrict__ edges){
  for (int i = bb * 256 + (int)threadIdx.x; i < n; i += SCAT_BPP * 256){
    int d = dp[i] + rb;
    if (d >= lo && d < hi){
      int s = sp[i];
      float ev = ep[s - zb];
      int pos = atomicAdd(&cursor[d], 1);
      edges[pos] = make_int2(s, __float_as_int(ev));
    }
  }
}
__global__ __launch_bounds__(256) void k_scat(ScatArgs a){
  const int p  = blockIdx.x & (NPART - 1);   // partition == XCD (round-robin dispatch)
  const int bb = blockIdx.x >> 3;
  const int lo = a.pb[p], hi = a.pb[p + 1];
  scat_stream(a.s0, a.d0, a.e0, a.nse, 0,         a.S, lo, hi, bb, a.cursor, a.edges);
  scat_stream(a.s1, a.d1, a.e1, a.nse, 0,         0,   lo, hi, bb, a.cursor, a.edges);
  scat_stream(a.s2, a.d2, a.e2, a.nek, a.S + a.E, a.E, lo, hi, bb, a.cursor, a.edges);
  scat_stream(a.s3, a.d3, a.e3, a.nek, a.S + a.E, 0,   lo, hi, bb, a.cursor, a.edges);
}

// ---------------- per-dst-segment softmax + weighted aggregation ----------------
template<int NWAVES, int MODE>
__global__ __launch_bounds__(NWAVES * 64) void k_agg(
    const int* __restrict__ offs, int segbase,
    const int2* __restrict__ edges,
    const __hip_bfloat16* __restrict__ Z, int zbase,
    const float* __restrict__ emb, float* __restrict__ out,
    const float* __restrict__ efk_buf,
    const float* __restrict__ attn0, const float* __restrict__ b0p,
    const float* __restrict__ attn1, const float* __restrict__ b1p)
{
  constexpr int NT = NWAVES * 64;
  constexpr int NSLOT = NWAVES * 4;
  __shared__ float sred[NWAVES];
  __shared__ float lacc[NWAVES][KD];
  const int tid = threadIdx.x;
  const int wave = tid >> 6, lane = tid & 63;
  const int sub = lane >> 4, li = lane & 15;
  const int seg = segbase + blockIdx.x;
  const int beg = offs[seg], end = offs[seg + 1];

  float m = -3.0e38f;
  for (int i = beg + tid; i < end; i += NT) m = fmaxf(m, __int_as_float(edges[i].y));
  m = wred_max(m);
  if (lane == 0) sred[wave] = m;
  __syncthreads();
  float mm = sred[0];
#pragma unroll
  for (int i = 1; i < NWAVES; ++i) mm = fmaxf(mm, sred[i]);
  __syncthreads();

  float ds = 0.f;
  for (int i = beg + tid; i < end; i += NT) ds += __expf(__int_as_float(edges[i].y) - mm);
  ds = wred_sum(ds);
  if (lane == 0) sred[wave] = ds;
  __syncthreads();
  float dsum = 0.f;
#pragma unroll
  for (int i = 0; i < NWAVES; ++i) dsum += sred[i];
  float rden = (end > beg) ? 1.f / dsum : 0.f;

  float acc[8];
#pragma unroll
  for (int j = 0; j < 8; ++j) acc[j] = 0.f;
  const int slot = wave * 4 + sub;
  for (int i = beg + slot; i < end; i += NSLOT){
    int2 ed = edges[i];
    float w = __expf(__int_as_float(ed.y) - mm);
    bf16x8 z = *(const bf16x8*)(Z + (size_t)(ed.x - zbase) * KD + li * 8);
#pragma unroll
    for (int j = 0; j < 8; ++j) acc[j] = fmaf(w, bf2f(z[j]), acc[j]);
  }
#pragma unroll
  for (int j = 0; j < 8; ++j){
    acc[j] += __shfl_xor(acc[j], 16, 64);
    acc[j] += __shfl_xor(acc[j], 32, 64);
  }
  __syncthreads();
  if (sub == 0){
    f32x4 v0, v1;
#pragma unroll
    for (int j = 0; j < 4; ++j){ v0[j] = acc[j]; v1[j] = acc[4 + j]; }
    *(f32x4*)&lacc[wave][li * 8]     = v0;
    *(f32x4*)&lacc[wave][li * 8 + 4] = v1;
  }
  __syncthreads();

  float accw = 0.f, ex = 0.f, ek = 0.f;
  if (tid < KD){
    float a = 0.f;
#pragma unroll
    for (int wv = 0; wv < NWAVES; ++wv) a += lacc[wv][tid];
    accw = a * rden;
    if (MODE == 1) ex = emb[(size_t)blockIdx.x * KD + tid];
    if (MODE == 2){
      ex = emb[(size_t)blockIdx.x * KD + tid];
      ek = efk_buf[(size_t)blockIdx.x * KD + tid];
    }
  }

  if (MODE == 0){
    if (tid < KD) out[(size_t)blockIdx.x * KD + tid] = accw;
  } else if (MODE == 1){
    if (tid < KD) out[(size_t)blockIdx.x * KD + tid] = ex + accw;
  } else {
    float q0 = 0.f, q1 = 0.f;
    if (tid < KD){
      q0 = ex * attn0[tid] + accw * attn0[KD + tid];
      q1 = ex * attn1[tid] + ek * attn1[KD + tid];
    }
    q0 = wred_sum(q0); q1 = wred_sum(q1);
    if (lane == 0) sred[wave] = q0;
    __syncthreads();
    float s0 = 0.f;
#pragma unroll
    for (int i = 0; i < NWAVES; ++i) s0 += sred[i];
    __syncthreads();
    if (lane == 0) sred[wave] = q1;
    __syncthreads();
    float s1 = 0.f;
#pragma unroll
    for (int i = 0; i < NWAVES; ++i) s1 += sred[i];
    float sc0 = s0 + b0p[0], sc1 = s1 + b1p[0];
    float mx = fmaxf(sc0, sc1);
    float w0 = __expf(sc0 - mx), w1 = __expf(sc1 - mx);
    float inv = 1.f / (w0 + w1);
    w0 *= inv; w1 *= inv;
    if (tid < KD) out[(size_t)blockIdx.x * KD + tid] = ex + w0 * accw + w1 * ek;
  }
}

extern "C" void kernel_launch(void* const* d_in, const int* in_sizes, int n_in,
                              void* d_out, int out_size, void* d_ws, size_t ws_size,
                              hipStream_t stream){
  const int S  = in_sizes[0] / KD;     // 40000
  const int E  = in_sizes[1] / KD;     // 18000
  const int KN = in_sizes[2] / KD;     // 128
  const int nse = in_sizes[19];        // 1.5M
  const int nek = in_sizes[23];        // 180K

  const float* stu  = (const float*)d_in[0];
  const float* exer = (const float*)d_in[1];
  const float* kn   = (const float*)d_in[2];
  const float* sfe_fcW = (const float*)d_in[3];  const float* sfe_attn = (const float*)d_in[4];
  const float* efs_fcW = (const float*)d_in[5];  const float* efs_attn = (const float*)d_in[6];
  const float* efk_fcW = (const float*)d_in[7];  const float* efk_attn = (const float*)d_in[8];
  const float* kfe_fcW = (const float*)d_in[9];  const float* kfe_attn = (const float*)d_in[10];
  const float* ea0W = (const float*)d_in[13]; const float* ea0b = (const float*)d_in[14];
  const float* ea1W = (const float*)d_in[15]; const float* ea1b = (const float*)d_in[16];
  const int* sfe_src = (const int*)d_in[19]; const int* sfe_dst = (const int*)d_in[20];
  const int* efs_src = (const int*)d_in[21]; const int* efs_dst = (const int*)d_in[22];
  const int* efk_src = (const int*)d_in[23]; const int* efk_dst = (const int*)d_in[24];
  const int* kfe_src = (const int*)d_in[25]; const int* kfe_dst = (const int*)d_in[26];
  float* out = (float*)d_out;

  // ---- workspace carve-up ----
  char* w = (char*)d_ws;
  auto alloc = [&](size_t bytes) -> char* {
    char* p = w; w += (bytes + 255) & ~(size_t)255; return p;
  };
  short* Wb               = (short*)alloc((size_t)4 * 16384 * 2);
  __hip_bfloat16* z_sfe   = (__hip_bfloat16*)alloc((size_t)E  * KD * 2);
  __hip_bfloat16* z_efs   = (__hip_bfloat16*)alloc((size_t)S  * KD * 2);
  __hip_bfloat16* z_efk   = (__hip_bfloat16*)alloc((size_t)KN * KD * 2);
  __hip_bfloat16* z_kfe   = (__hip_bfloat16*)alloc((size_t)E  * KD * 2);
  float* es_sfe = (float*)alloc((size_t)E  * 4);
  float* es_efs = (float*)alloc((size_t)S  * 4);
  float* es_efk = (float*)alloc((size_t)KN * 4);
  float* es_kfe = (float*)alloc((size_t)E  * 4);
  float* efk_buf = (float*)alloc((size_t)E * KD * 4);
  const int NSEG = S + E + E + KN;     // 76128
  int* cnt8   = (int*)alloc((size_t)NPART * NSEG * 4);
  int* cnt    = (int*)alloc((size_t)NSEG * 4);
  int* offs   = (int*)alloc((size_t)(NSEG + 1) * 4);
  int* cursor = (int*)alloc((size_t)NSEG * 4);
  int* bsum   = (int*)alloc(1024 * 4);
  int* pb     = (int*)alloc((NPART + 1) * 4);
  const size_t TOTE = 2 * (size_t)nse + 2 * (size_t)nek;
  int2* edges = (int2*)alloc(TOTE * 8);

  hipMemsetAsync(cnt8, 0, (size_t)NPART * NSEG * 4, stream);

  k_cvt_w<<<256, 256, 0, stream>>>(sfe_fcW, efs_fcW, efk_fcW, kfe_fcW, Wb);

  // mega1: hist (2048 blocks, per-XCD private) + 4 gemm jobs
  const int nbE = (E + 63) / 64, nbS = (S + 63) / 64, nbK = (KN + 63) / 64;
  Mega1Args ma;
  ma.d0 = sfe_dst; ma.d1 = efs_dst; ma.d2 = efk_dst; ma.d3 = kfe_dst;
  ma.nse = nse; ma.nek = nek; ma.rebase23 = S + E; ma.nseg = NSEG; ma.cnt8 = cnt8;
  ma.A0 = exer; ma.nA = E; ma.Wb = Wb;
  ma.j[0] = { stu, sfe_attn, z_sfe, es_sfe, S, E,  0,                 0 };
  ma.j[1] = { stu, efs_attn, z_efs, es_efs, 0, S,  nbE,               16384 };
  ma.j[2] = { kn,  efk_attn, z_efk, es_efk, E, KN, nbE + nbS,         32768 };
  ma.j[3] = { kn,  kfe_attn, z_kfe, es_kfe, 0, E,  nbE + nbS + nbK,   49152 };
  const int NBG = nbE + nbS + nbK + nbE;
  k_mega1<<<NBH + NBG, 256, 0, stream>>>(ma);

  int nb = (NSEG + 1023) / 1024;
  k_scan1<<<nb, 1024, 0, stream>>>(cnt8, cnt, NSEG, offs, bsum);
  k_scan2<<<1, 1024, 0, stream>>>(bsum, nb);
  k_scan3<<<nb, 1024, 0, stream>>>(cnt, NSEG, offs, bsum, cursor);
  k_pbound<<<1, NPART + 1, 0, stream>>>(offs, NSEG, (long)TOTE, pb);

  ScatArgs sa;
  sa.s0 = sfe_src; sa.d0 = sfe_dst; sa.s1 = efs_src; sa.d1 = efs_dst;
  sa.s2 = efk_src; sa.d2 = efk_dst; sa.s3 = kfe_src; sa.d3 = kfe_dst;
  sa.e0 = es_sfe; sa.e1 = es_efs; sa.e2 = es_efk; sa.e3 = es_kfe;
  sa.nse = nse; sa.nek = nek; sa.S = S; sa.E = E;
  sa.cursor = cursor; sa.edges = edges;
  sa.pb = pb;
  k_scat<<<NPART * SCAT_BPP, 256, 0, stream>>>(sa);

  // aggregations (efk first: its buffer feeds the exercise combine)
  k_agg<2, 0><<<E, 128, 0, stream>>>(offs, S + E,     edges, z_efk, E, nullptr, efk_buf,
                                     nullptr, nullptr, nullptr, nullptr, nullptr);
  k_agg<4, 1><<<S, 256, 0, stream>>>(offs, 0,         edges, z_sfe, S, stu, out,
                                     nullptr, nullptr, nullptr, nullptr, nullptr);
  k_agg<16, 1><<<KN, 1024, 0, stream>>>(offs, S + 2 * E, edges, z_kfe, 0, kn,
                                        out + (size_t)(S + E) * KD,
                                        nullptr, nullptr, nullptr, nullptr, nullptr);
  k_agg<4, 2><<<E, 256, 0, stream>>>(offs, S,         edges, z_efs, 0, exer,
                                     out + (size_t)S * KD,
                                     efk_buf, ea0W, ea0b, ea1W, ea1b);
}

// Round 6
// 756.465 us; speedup vs baseline: 1.1729x; 1.0295x over previous
//
#include <hip/hip_runtime.h>
#include <hip/hip_bf16.h>

using f32x4  = __attribute__((ext_vector_type(4))) float;
using bf16x8 = __attribute__((ext_vector_type(8))) short;

#define KD 128
#define NBH 2048      // hist blocks inside mega1
#define NPART 8       // partitions (== XCDs)
#define SCAT_BPP 448  // scatter blocks per partition (B0+B1+B2+B3)
#define SB0 192
#define SB1 192
#define SB2 32
#define SB3 32

__device__ inline float wred_sum(float v){
#pragma unroll
  for (int o = 32; o > 0; o >>= 1) v += __shfl_xor(v, o, 64);
  return v;
}
__device__ inline float wred_max(float v){
#pragma unroll
  for (int o = 32; o > 0; o >>= 1) v = fmaxf(v, __shfl_xor(v, o, 64));
  return v;
}
__device__ inline float bf2f(short s){
  return __uint_as_float(((unsigned int)(unsigned short)s) << 16);
}

// ---------------- weight convert: 4x [128][128] f32 -> bf16 ----------------
__global__ __launch_bounds__(256) void k_cvt_w(const float* __restrict__ w0,
                                               const float* __restrict__ w1,
                                               const float* __restrict__ w2,
                                               const float* __restrict__ w3,
                                               short* __restrict__ out){
  int i = blockIdx.x * 256 + threadIdx.x;            // 0..65535
  const float* src = (i < 16384) ? w0 : (i < 32768) ? w1 : (i < 49152) ? w2 : w3;
  float v = src[i & 16383];
  __hip_bfloat16 b = __float2bfloat16(v);
  out[i] = __builtin_bit_cast(short, b);
}

// ---------------- GEMM body: z = h @ W^T  (+ es = z . attn[:128]) ----------------
__device__ void gemm_body(const float* __restrict__ A0, int nA,
                          const float* __restrict__ A1,
                          const short* __restrict__ Wb, const float* __restrict__ attn,
                          __hip_bfloat16* __restrict__ Z, float* __restrict__ es,
                          int zbase, int nrows, int blk)
{
  const int wave = threadIdx.x >> 6, lane = threadIdx.x & 63;
  const int lr = lane & 15, lk = lane >> 4;
  const int row0 = blk * 64 + wave * 16;

  bf16x8 afrag[4];
  {
    int r = row0 + lr;
    bool rv = (r < nrows);
    int node = zbase + r;
    const float* ap = A0;
    if (rv) ap = (node < nA) ? (A0 + (size_t)node * KD) : (A1 + (size_t)(node - nA) * KD);
#pragma unroll
    for (int t = 0; t < 4; ++t){
      float x[8];
      if (rv){
        float4 u0 = *(const float4*)(ap + t * 32 + lk * 8);
        float4 u1 = *(const float4*)(ap + t * 32 + lk * 8 + 4);
        x[0]=u0.x; x[1]=u0.y; x[2]=u0.z; x[3]=u0.w;
        x[4]=u1.x; x[5]=u1.y; x[6]=u1.z; x[7]=u1.w;
      } else {
#pragma unroll
        for (int j = 0; j < 8; ++j) x[j] = 0.f;
      }
      bf16x8 af;
#pragma unroll
      for (int j = 0; j < 8; ++j){
        __hip_bfloat16 b = __float2bfloat16(x[j]);
        af[j] = __builtin_bit_cast(short, b);
      }
      afrag[t] = af;
    }
  }

  f32x4 acc[8];
#pragma unroll
  for (int c = 0; c < 8; ++c){ acc[c][0]=0.f; acc[c][1]=0.f; acc[c][2]=0.f; acc[c][3]=0.f; }

#pragma unroll
  for (int c = 0; c < 8; ++c){
#pragma unroll
    for (int t = 0; t < 4; ++t){
      bf16x8 bf = *(const bf16x8*)(Wb + (c * 16 + lr) * KD + t * 32 + lk * 8);
      acc[c] = __builtin_amdgcn_mfma_f32_16x16x32_bf16(afrag[t], bf, acc[c], 0, 0, 0);
    }
  }

  float p[4] = {0.f, 0.f, 0.f, 0.f};
#pragma unroll
  for (int c = 0; c < 8; ++c){
    float av = attn[c * 16 + lr];
#pragma unroll
    for (int q = 0; q < 4; ++q){
      int r = row0 + lk * 4 + q;
      if (r < nrows) Z[(size_t)r * KD + c * 16 + lr] = __float2bfloat16(acc[c][q]);
      p[q] += acc[c][q] * av;
    }
  }
#pragma unroll
  for (int q = 0; q < 4; ++q){
#pragma unroll
    for (int o = 1; o < 16; o <<= 1) p[q] += __shfl_xor(p[q], o, 64);
  }
  if (lr == 0){
#pragma unroll
    for (int q = 0; q < 4; ++q){
      int r = row0 + lk * 4 + q;
      if (r < nrows) es[r] = p[q];
    }
  }
}

// ---------------- mega1: hist blocks (per-XCD privatized) + gemm blocks ----------------
struct GJob { const float* A1; const float* attn; __hip_bfloat16* Z; float* es;
              int zbase, nrows, blk0, wboff; };
struct Mega1Args {
  const int* d0; const int* d1; const int* d2; const int* d3;
  int nse, nek, rebase23, nseg;
  int* cnt8;                       // [NPART][nseg]
  const float* A0; int nA;
  const short* Wb;
  GJob j[4];
};

__global__ __launch_bounds__(256) void k_mega1(Mega1Args a){
  int b = blockIdx.x;
  if (b < NBH){
    int* cnt = a.cnt8 + (size_t)(b & (NPART - 1)) * a.nseg;
    long total = 2L * a.nse + 2L * a.nek;
    for (long i = (long)b * 256 + threadIdx.x; i < total; i += (long)NBH * 256){
      long k = i; const int* dp; int rb;
      if (k < a.nse){ dp = a.d0; rb = 0; }
      else if ((k -= a.nse) < a.nse){ dp = a.d1; rb = 0; }
      else if ((k -= a.nse) < a.nek){ dp = a.d2; rb = a.rebase23; }
      else { k -= a.nek; dp = a.d3; rb = a.rebase23; }
      atomicAdd(&cnt[dp[k] + rb], 1);
    }
  } else {
    int gb = b - NBH;
    int ji = 3;
    if (gb < a.j[1].blk0) ji = 0;
    else if (gb < a.j[2].blk0) ji = 1;
    else if (gb < a.j[3].blk0) ji = 2;
    GJob J = a.j[ji];
    gemm_body(a.A0, a.nA, J.A1, a.Wb + J.wboff, J.attn, J.Z, J.es,
              J.zbase, J.nrows, gb - J.blk0);
  }
}

// ---------------- scan (scan1 merges the 8 private histograms) ----------------
__global__ __launch_bounds__(1024) void k_scan1(const int* __restrict__ cnt8,
                                                int* __restrict__ cnt, int n,
                                                int* __restrict__ offs, int* __restrict__ bsum){
  __shared__ int sh[1024];
  int tid = threadIdx.x;
  int i = blockIdx.x * 1024 + tid;
  int v = 0;
  if (i < n){
#pragma unroll
    for (int p = 0; p < NPART; ++p) v += cnt8[(size_t)p * n + i];
    cnt[i] = v;
  }
  sh[tid] = v; __syncthreads();
  for (int o = 1; o < 1024; o <<= 1){
    int u = (tid >= o) ? sh[tid - o] : 0;
    __syncthreads();
    sh[tid] += u;
    __syncthreads();
  }
  if (i < n) offs[i + 1] = sh[tid];
  if (tid == 1023) bsum[blockIdx.x] = sh[tid];
}
__global__ __launch_bounds__(1024) void k_scan2(int* __restrict__ bsum, int nb){
  __shared__ int sh[1024];
  int tid = threadIdx.x;
  int v = (tid < nb) ? bsum[tid] : 0;
  sh[tid] = v; __syncthreads();
  for (int o = 1; o < 1024; o <<= 1){
    int u = (tid >= o) ? sh[tid - o] : 0;
    __syncthreads();
    sh[tid] += u;
    __syncthreads();
  }
  if (tid < nb) bsum[tid] = sh[tid] - v;   // exclusive
}
__global__ __launch_bounds__(1024) void k_scan3(const int* __restrict__ cnt, int n,
                                                int* __restrict__ offs,
                                                const int* __restrict__ bsum,
                                                int* __restrict__ cursor){
  int i = blockIdx.x * 1024 + threadIdx.x;
  if (i < n){
    int incl = offs[i + 1] + bsum[i >> 10];
    offs[i + 1] = incl;
    cursor[i] = incl - cnt[i];
    if (i == 0) offs[0] = 0;
  }
}

// ---------------- partition bounds: 8 edge-balanced seg ranges ----------------
__global__ void k_pbound(const int* __restrict__ offs, int nseg, long tote,
                         int* __restrict__ pb){
  int p = threadIdx.x;          // 0..NPART
  if (p > NPART) return;
  if (p == 0){ pb[0] = 0; return; }
  if (p == NPART){ pb[NPART] = nseg; return; }
  long target = (tote * p) / NPART;
  int lo = 0, hi = nseg;
  while (lo < hi){
    int mid = (lo + hi) >> 1;
    if ((long)offs[mid] >= target) hi = mid; else lo = mid + 1;
  }
  pb[p] = lo;
}

// ---------------- scatter: XCD-partitioned, src-only payload ----------------
struct ScatArgs {
  const int* s0; const int* d0; const int* s1; const int* d1;
  const int* s2; const int* d2; const int* s3; const int* d3;
  int nse, nek, S, E;
  int* cursor; int* edges;
  const int* pb;
};
__device__ inline void scat_stream(const int* __restrict__ sp, const int* __restrict__ dp,
                                   int n, int rb, int lo, int hi, int bb, int nb,
                                   int* __restrict__ cursor, int* __restrict__ edges){
  for (int i = bb * 256 + (int)threadIdx.x; i < n; i += nb * 256){
    int d = dp[i] + rb;
    if (d >= lo && d < hi){
      int s = sp[i];
      int pos = atomicAdd(&cursor[d], 1);
      edges[pos] = s;
    }
  }
}
__global__ __launch_bounds__(256) void k_scat(ScatArgs a){
  const int p  = blockIdx.x & (NPART - 1);   // partition == XCD (round-robin dispatch)
  const int bq = blockIdx.x >> 3;            // 0..SCAT_BPP-1
  const int lo = a.pb[p], hi = a.pb[p + 1];
  if (bq < SB0)
    scat_stream(a.s0, a.d0, a.nse, 0,         lo, hi, bq,             SB0, a.cursor, a.edges);
  else if (bq < SB0 + SB1)
    scat_stream(a.s1, a.d1, a.nse, 0,         lo, hi, bq - SB0,       SB1, a.cursor, a.edges);
  else if (bq < SB0 + SB1 + SB2)
    scat_stream(a.s2, a.d2, a.nek, a.S + a.E, lo, hi, bq - SB0 - SB1, SB2, a.cursor, a.edges);
  else
    scat_stream(a.s3, a.d3, a.nek, a.S + a.E, lo, hi, bq - SB0 - SB1 - SB2, SB3, a.cursor, a.edges);
}

// ---------------- per-dst-segment softmax + weighted aggregation ----------------
// edges hold absolute src; es/Z indexed by (src - zbase).
template<int NWAVES, int MODE>
__global__ __launch_bounds__(NWAVES * 64) void k_agg(
    const int* __restrict__ offs, int segbase,
    const int* __restrict__ edges, const float* __restrict__ esp,
    const __hip_bfloat16* __restrict__ Z, int zbase,
    const float* __restrict__ emb, float* __restrict__ out,
    const float* __restrict__ efk_buf,
    const float* __restrict__ attn0, const float* __restrict__ b0p,
    const float* __restrict__ attn1, const float* __restrict__ b1p)
{
  constexpr int NT = NWAVES * 64;
  constexpr int NSLOT = NWAVES * 4;
  __shared__ float sred[NWAVES];
  __shared__ float lacc[NWAVES][KD];
  const int tid = threadIdx.x;
  const int wave = tid >> 6, lane = tid & 63;
  const int sub = lane >> 4, li = lane & 15;
  const int seg = segbase + blockIdx.x;
  const int beg = offs[seg], end = offs[seg + 1];

  float m = -3.0e38f;
  for (int i = beg + tid; i < end; i += NT) m = fmaxf(m, esp[edges[i] - zbase]);
  m = wred_max(m);
  if (lane == 0) sred[wave] = m;
  __syncthreads();
  float mm = sred[0];
#pragma unroll
  for (int i = 1; i < NWAVES; ++i) mm = fmaxf(mm, sred[i]);
  __syncthreads();

  float ds = 0.f;
  for (int i = beg + tid; i < end; i += NT) ds += __expf(esp[edges[i] - zbase] - mm);
  ds = wred_sum(ds);
  if (lane == 0) sred[wave] = ds;
  __syncthreads();
  float dsum = 0.f;
#pragma unroll
  for (int i = 0; i < NWAVES; ++i) dsum += sred[i];
  float rden = (end > beg) ? 1.f / dsum : 0.f;

  float acc[8];
#pragma unroll
  for (int j = 0; j < 8; ++j) acc[j] = 0.f;
  const int slot = wave * 4 + sub;
  for (int i = beg + slot; i < end; i += NSLOT){
    int r = edges[i] - zbase;
    float w = __expf(esp[r] - mm);
    bf16x8 z = *(const bf16x8*)(Z + (size_t)r * KD + li * 8);
#pragma unroll
    for (int j = 0; j < 8; ++j) acc[j] = fmaf(w, bf2f(z[j]), acc[j]);
  }
#pragma unroll
  for (int j = 0; j < 8; ++j){
    acc[j] += __shfl_xor(acc[j], 16, 64);
    acc[j] += __shfl_xor(acc[j], 32, 64);
  }
  __syncthreads();
  if (sub == 0){
    f32x4 v0, v1;
#pragma unroll
    for (int j = 0; j < 4; ++j){ v0[j] = acc[j]; v1[j] = acc[4 + j]; }
    *(f32x4*)&lacc[wave][li * 8]     = v0;
    *(f32x4*)&lacc[wave][li * 8 + 4] = v1;
  }
  __syncthreads();

  float accw = 0.f, ex = 0.f, ek = 0.f;
  if (tid < KD){
    float a = 0.f;
#pragma unroll
    for (int wv = 0; wv < NWAVES; ++wv) a += lacc[wv][tid];
    accw = a * rden;
    if (MODE == 1) ex = emb[(size_t)blockIdx.x * KD + tid];
    if (MODE == 2){
      ex = emb[(size_t)blockIdx.x * KD + tid];
      ek = efk_buf[(size_t)blockIdx.x * KD + tid];
    }
  }

  if (MODE == 0){
    if (tid < KD) out[(size_t)blockIdx.x * KD + tid] = accw;
  } else if (MODE == 1){
    if (tid < KD) out[(size_t)blockIdx.x * KD + tid] = ex + accw;
  } else {
    float q0 = 0.f, q1 = 0.f;
    if (tid < KD){
      q0 = ex * attn0[tid] + accw * attn0[KD + tid];
      q1 = ex * attn1[tid] + ek * attn1[KD + tid];
    }
    q0 = wred_sum(q0); q1 = wred_sum(q1);
    if (lane == 0) sred[wave] = q0;
    __syncthreads();
    float s0 = 0.f;
#pragma unroll
    for (int i = 0; i < NWAVES; ++i) s0 += sred[i];
    __syncthreads();
    if (lane == 0) sred[wave] = q1;
    __syncthreads();
    float s1 = 0.f;
#pragma unroll
    for (int i = 0; i < NWAVES; ++i) s1 += sred[i];
    float sc0 = s0 + b0p[0], sc1 = s1 + b1p[0];
    float mx = fmaxf(sc0, sc1);
    float w0 = __expf(sc0 - mx), w1 = __expf(sc1 - mx);
    float inv = 1.f / (w0 + w1);
    w0 *= inv; w1 *= inv;
    if (tid < KD) out[(size_t)blockIdx.x * KD + tid] = ex + w0 * accw + w1 * ek;
  }
}

extern "C" void kernel_launch(void* const* d_in, const int* in_sizes, int n_in,
                              void* d_out, int out_size, void* d_ws, size_t ws_size,
                              hipStream_t stream){
  const int S  = in_sizes[0] / KD;     // 40000
  const int E  = in_sizes[1] / KD;     // 18000
  const int KN = in_sizes[2] / KD;     // 128
  const int nse = in_sizes[19];        // 1.5M
  const int nek = in_sizes[23];        // 180K

  const float* stu  = (const float*)d_in[0];
  const float* exer = (const float*)d_in[1];
  const float* kn   = (const float*)d_in[2];
  const float* sfe_fcW = (const float*)d_in[3];  const float* sfe_attn = (const float*)d_in[4];
  const float* efs_fcW = (const float*)d_in[5];  const float* efs_attn = (const float*)d_in[6];
  const float* efk_fcW = (const float*)d_in[7];  const float* efk_attn = (const float*)d_in[8];
  const float* kfe_fcW = (const float*)d_in[9];  const float* kfe_attn = (const float*)d_in[10];
  const float* ea0W = (const float*)d_in[13]; const float* ea0b = (const float*)d_in[14];
  const float* ea1W = (const float*)d_in[15]; const float* ea1b = (const float*)d_in[16];
  const int* sfe_src = (const int*)d_in[19]; const int* sfe_dst = (const int*)d_in[20];
  const int* efs_src = (const int*)d_in[21]; const int* efs_dst = (const int*)d_in[22];
  const int* efk_src = (const int*)d_in[23]; const int* efk_dst = (const int*)d_in[24];
  const int* kfe_src = (const int*)d_in[25]; const int* kfe_dst = (const int*)d_in[26];
  float* out = (float*)d_out;

  // ---- workspace carve-up ----
  char* w = (char*)d_ws;
  auto alloc = [&](size_t bytes) -> char* {
    char* p = w; w += (bytes + 255) & ~(size_t)255; return p;
  };
  short* Wb               = (short*)alloc((size_t)4 * 16384 * 2);
  __hip_bfloat16* z_sfe   = (__hip_bfloat16*)alloc((size_t)E  * KD * 2);
  __hip_bfloat16* z_efs   = (__hip_bfloat16*)alloc((size_t)S  * KD * 2);
  __hip_bfloat16* z_efk   = (__hip_bfloat16*)alloc((size_t)KN * KD * 2);
  __hip_bfloat16* z_kfe   = (__hip_bfloat16*)alloc((size_t)E  * KD * 2);
  float* es_sfe = (float*)alloc((size_t)E  * 4);
  float* es_efs = (float*)alloc((size_t)S  * 4);
  float* es_efk = (float*)alloc((size_t)KN * 4);
  float* es_kfe = (float*)alloc((size_t)E  * 4);
  float* efk_buf = (float*)alloc((size_t)E * KD * 4);
  const int NSEG = S + E + E + KN;     // 76128
  int* cnt8   = (int*)alloc((size_t)NPART * NSEG * 4);
  int* cnt    = (int*)alloc((size_t)NSEG * 4);
  int* offs   = (int*)alloc((size_t)(NSEG + 1) * 4);
  int* cursor = (int*)alloc((size_t)NSEG * 4);
  int* bsum   = (int*)alloc(1024 * 4);
  int* pb     = (int*)alloc((NPART + 1) * 4);
  const size_t TOTE = 2 * (size_t)nse + 2 * (size_t)nek;
  int* edges  = (int*)alloc(TOTE * 4);

  hipMemsetAsync(cnt8, 0, (size_t)NPART * NSEG * 4, stream);

  k_cvt_w<<<256, 256, 0, stream>>>(sfe_fcW, efs_fcW, efk_fcW, kfe_fcW, Wb);

  // mega1: hist (2048 blocks, per-XCD private) + 4 gemm jobs
  const int nbE = (E + 63) / 64, nbS = (S + 63) / 64, nbK = (KN + 63) / 64;
  Mega1Args ma;
  ma.d0 = sfe_dst; ma.d1 = efs_dst; ma.d2 = efk_dst; ma.d3 = kfe_dst;
  ma.nse = nse; ma.nek = nek; ma.rebase23 = S + E; ma.nseg = NSEG; ma.cnt8 = cnt8;
  ma.A0 = exer; ma.nA = E; ma.Wb = Wb;
  ma.j[0] = { stu, sfe_attn, z_sfe, es_sfe, S, E,  0,                 0 };
  ma.j[1] = { stu, efs_attn, z_efs, es_efs, 0, S,  nbE,               16384 };
  ma.j[2] = { kn,  efk_attn, z_efk, es_efk, E, KN, nbE + nbS,         32768 };
  ma.j[3] = { kn,  kfe_attn, z_kfe, es_kfe, 0, E,  nbE + nbS + nbK,   49152 };
  const int NBG = nbE + nbS + nbK + nbE;
  k_mega1<<<NBH + NBG, 256, 0, stream>>>(ma);

  int nb = (NSEG + 1023) / 1024;
  k_scan1<<<nb, 1024, 0, stream>>>(cnt8, cnt, NSEG, offs, bsum);
  k_scan2<<<1, 1024, 0, stream>>>(bsum, nb);
  k_scan3<<<nb, 1024, 0, stream>>>(cnt, NSEG, offs, bsum, cursor);
  k_pbound<<<1, NPART + 1, 0, stream>>>(offs, NSEG, (long)TOTE, pb);

  ScatArgs sa;
  sa.s0 = sfe_src; sa.d0 = sfe_dst; sa.s1 = efs_src; sa.d1 = efs_dst;
  sa.s2 = efk_src; sa.d2 = efk_dst; sa.s3 = kfe_src; sa.d3 = kfe_dst;
  sa.nse = nse; sa.nek = nek; sa.S = S; sa.E = E;
  sa.cursor = cursor; sa.edges = edges;
  sa.pb = pb;
  k_scat<<<NPART * SCAT_BPP, 256, 0, stream>>>(sa);

  // aggregations (efk first: its buffer feeds the exercise combine)
  k_agg<2, 0><<<E, 128, 0, stream>>>(offs, S + E,     edges, es_efk, z_efk, E, nullptr, efk_buf,
                                     nullptr, nullptr, nullptr, nullptr, nullptr);
  k_agg<4, 1><<<S, 256, 0, stream>>>(offs, 0,         edges, es_sfe, z_sfe, S, stu, out,
                                     nullptr, nullptr, nullptr, nullptr, nullptr);
  k_agg<16, 1><<<KN, 1024, 0, stream>>>(offs, S + 2 * E, edges, es_kfe, z_kfe, 0, kn,
                                        out + (size_t)(S + E) * KD,
                                        nullptr, nullptr, nullptr, nullptr, nullptr);
  k_agg<4, 2><<<E, 256, 0, stream>>>(offs, S,         edges, es_efs, z_efs, 0, exer,
                                     out + (size_t)S * KD,
                                     efk_buf, ea0W, ea0b, ea1W, ea1b);
}

// Round 7
// 702.170 us; speedup vs baseline: 1.2636x; 1.0773x over previous
//
#include <hip/hip_runtime.h>
#include <hip/hip_bf16.h>

using f32x4  = __attribute__((ext_vector_type(4))) float;
using bf16x8 = __attribute__((ext_vector_type(8))) short;
typedef unsigned long long u64;

#define KD 128
#define NBB 256       // bin+hist blocks inside mega1
#define NPART 8       // partitions (== XCDs)
#define BINCAP 512
#define FLUSHN 256
#define SCATB_BPP 128 // scatB blocks per partition

__device__ inline float wred_sum(float v){
#pragma unroll
  for (int o = 32; o > 0; o >>= 1) v += __shfl_xor(v, o, 64);
  return v;
}
__device__ inline float wred_max(float v){
#pragma unroll
  for (int o = 32; o > 0; o >>= 1) v = fmaxf(v, __shfl_xor(v, o, 64));
  return v;
}
__device__ inline float bf2f(short s){
  return __uint_as_float(((unsigned int)(unsigned short)s) << 16);
}

struct PB { int v[9]; };

// ---------------- weight convert: 4x [128][128] f32 -> bf16 ----------------
__global__ __launch_bounds__(256) void k_cvt_w(const float* __restrict__ w0,
                                               const float* __restrict__ w1,
                                               const float* __restrict__ w2,
                                               const float* __restrict__ w3,
                                               short* __restrict__ out){
  int i = blockIdx.x * 256 + threadIdx.x;            // 0..65535
  const float* src = (i < 16384) ? w0 : (i < 32768) ? w1 : (i < 49152) ? w2 : w3;
  float v = src[i & 16383];
  __hip_bfloat16 b = __float2bfloat16(v);
  out[i] = __builtin_bit_cast(short, b);
}

// ---------------- GEMM body: z = h @ W^T  (+ es = z . attn[:128]) ----------------
__device__ void gemm_body(const float* __restrict__ A0, int nA,
                          const float* __restrict__ A1,
                          const short* __restrict__ Wb, const float* __restrict__ attn,
                          __hip_bfloat16* __restrict__ Z, float* __restrict__ es,
                          int zbase, int nrows, int blk)
{
  const int wave = threadIdx.x >> 6, lane = threadIdx.x & 63;
  const int lr = lane & 15, lk = lane >> 4;
  const int row0 = blk * 64 + wave * 16;

  bf16x8 afrag[4];
  {
    int r = row0 + lr;
    bool rv = (r < nrows);
    int node = zbase + r;
    const float* ap = A0;
    if (rv) ap = (node < nA) ? (A0 + (size_t)node * KD) : (A1 + (size_t)(node - nA) * KD);
#pragma unroll
    for (int t = 0; t < 4; ++t){
      float x[8];
      if (rv){
        float4 u0 = *(const float4*)(ap + t * 32 + lk * 8);
        float4 u1 = *(const float4*)(ap + t * 32 + lk * 8 + 4);
        x[0]=u0.x; x[1]=u0.y; x[2]=u0.z; x[3]=u0.w;
        x[4]=u1.x; x[5]=u1.y; x[6]=u1.z; x[7]=u1.w;
      } else {
#pragma unroll
        for (int j = 0; j < 8; ++j) x[j] = 0.f;
      }
      bf16x8 af;
#pragma unroll
      for (int j = 0; j < 8; ++j){
        __hip_bfloat16 b = __float2bfloat16(x[j]);
        af[j] = __builtin_bit_cast(short, b);
      }
      afrag[t] = af;
    }
  }

  f32x4 acc[8];
#pragma unroll
  for (int c = 0; c < 8; ++c){ acc[c][0]=0.f; acc[c][1]=0.f; acc[c][2]=0.f; acc[c][3]=0.f; }

#pragma unroll
  for (int c = 0; c < 8; ++c){
#pragma unroll
    for (int t = 0; t < 4; ++t){
      bf16x8 bf = *(const bf16x8*)(Wb + (c * 16 + lr) * KD + t * 32 + lk * 8);
      acc[c] = __builtin_amdgcn_mfma_f32_16x16x32_bf16(afrag[t], bf, acc[c], 0, 0, 0);
    }
  }

  float p[4] = {0.f, 0.f, 0.f, 0.f};
#pragma unroll
  for (int c = 0; c < 8; ++c){
    float av = attn[c * 16 + lr];
#pragma unroll
    for (int q = 0; q < 4; ++q){
      int r = row0 + lk * 4 + q;
      if (r < nrows) Z[(size_t)r * KD + c * 16 + lr] = __float2bfloat16(acc[c][q]);
      p[q] += acc[c][q] * av;
    }
  }
#pragma unroll
  for (int q = 0; q < 4; ++q){
#pragma unroll
    for (int o = 1; o < 16; o <<= 1) p[q] += __shfl_xor(p[q], o, 64);
  }
  if (lr == 0){
#pragma unroll
    for (int q = 0; q < 4; ++q){
      int r = row0 + lk * 4 + q;
      if (r < nrows) es[r] = p[q];
    }
  }
}

// ---------------- mega1: bin+hist blocks + gemm blocks ----------------
struct GJob { const float* A1; const float* attn; __hip_bfloat16* Z; float* es;
              int zbase, nrows, blk0, wboff; };
struct Mega1Args {
  const int* d0; const int* s0; const int* d1; const int* s1;
  const int* d2; const int* s2; const int* d3; const int* s3;
  int nse, nek, rebase23, nseg;
  int* cnt8;                       // [NPART][nseg]
  u64* buckets; int capp;          // [NPART][capp]
  int* gcur;                       // [NPART]
  PB pb;
  const float* A0; int nA;
  const short* Wb;
  GJob j[4];
};

__global__ __launch_bounds__(256) void k_mega1(Mega1Args a){
  __shared__ u64 lbin[NPART][BINCAP];
  __shared__ int lcnt[NPART];
  __shared__ int sbase;
  int b = blockIdx.x;
  int tid = threadIdx.x;
  if (b < NBB){
    int* cnt = a.cnt8 + (size_t)(b & (NPART - 1)) * a.nseg;
    if (tid < NPART) lcnt[tid] = 0;
    __syncthreads();
    long total = 2L * a.nse + 2L * a.nek;
    long chunk = (total + NBB - 1) / NBB;
    long c0 = b * chunk, c1 = c0 + chunk;
    if (c1 > total) c1 = total;
    int niter = (c1 > c0) ? (int)((c1 - c0 + 255) >> 8) : 0;
    for (int it = 0; it < niter; ++it){
      long i = c0 + (long)it * 256 + tid;
      if (i < c1){
        long k = i; const int* dp; const int* sp; int rb;
        if (k < a.nse){ dp = a.d0; sp = a.s0; rb = 0; }
        else if ((k -= a.nse) < a.nse){ dp = a.d1; sp = a.s1; rb = 0; }
        else if ((k -= a.nse) < a.nek){ dp = a.d2; sp = a.s2; rb = a.rebase23; }
        else { k -= a.nek; dp = a.d3; sp = a.s3; rb = a.rebase23; }
        int seg = dp[k] + rb;
        int src = sp[k];
        atomicAdd(&cnt[seg], 1);
        int p = 0;
#pragma unroll
        for (int jj = 1; jj < NPART; ++jj) p += (seg >= a.pb.v[jj]);
        int idx = atomicAdd(&lcnt[p], 1);
        lbin[p][idx] = ((u64)(unsigned)seg << 32) | (unsigned)src;
      }
      __syncthreads();
#pragma unroll
      for (int pp = 0; pp < NPART; ++pp){
        int c = lcnt[pp];
        if (c >= FLUSHN){
          if (tid == 0) sbase = atomicAdd(&a.gcur[pp], FLUSHN);
          __syncthreads();
          u64 e = lbin[pp][tid];
          __builtin_nontemporal_store(e, &a.buckets[(size_t)pp * a.capp + sbase + tid]);
          __syncthreads();
          if (tid < c - FLUSHN) lbin[pp][tid] = lbin[pp][FLUSHN + tid];
          if (tid == 0) lcnt[pp] = c - FLUSHN;
        }
        __syncthreads();
      }
    }
    // drain
    for (int pp = 0; pp < NPART; ++pp){
      int c = lcnt[pp];
      if (c > 0){
        if (tid == 0) sbase = atomicAdd(&a.gcur[pp], c);
        __syncthreads();
        if (tid < c){
          u64 e = lbin[pp][tid];
          __builtin_nontemporal_store(e, &a.buckets[(size_t)pp * a.capp + sbase + tid]);
        }
      }
      __syncthreads();
    }
  } else {
    int gb = b - NBB;
    int ji = 3;
    if (gb < a.j[1].blk0) ji = 0;
    else if (gb < a.j[2].blk0) ji = 1;
    else if (gb < a.j[3].blk0) ji = 2;
    GJob J = a.j[ji];
    gemm_body(a.A0, a.nA, J.A1, a.Wb + J.wboff, J.attn, J.Z, J.es,
              J.zbase, J.nrows, gb - J.blk0);
  }
}

// ---------------- scan (scan1 merges the 8 private histograms) ----------------
__global__ __launch_bounds__(1024) void k_scan1(const int* __restrict__ cnt8,
                                                int* __restrict__ cnt, int n,
                                                int* __restrict__ offs, int* __restrict__ bsum){
  __shared__ int sh[1024];
  int tid = threadIdx.x;
  int i = blockIdx.x * 1024 + tid;
  int v = 0;
  if (i < n){
#pragma unroll
    for (int p = 0; p < NPART; ++p) v += cnt8[(size_t)p * n + i];
    cnt[i] = v;
  }
  sh[tid] = v; __syncthreads();
  for (int o = 1; o < 1024; o <<= 1){
    int u = (tid >= o) ? sh[tid - o] : 0;
    __syncthreads();
    sh[tid] += u;
    __syncthreads();
  }
  if (i < n) offs[i + 1] = sh[tid];
  if (tid == 1023) bsum[blockIdx.x] = sh[tid];
}
__global__ __launch_bounds__(1024) void k_scan2(int* __restrict__ bsum, int nb){
  __shared__ int sh[1024];
  int tid = threadIdx.x;
  int v = (tid < nb) ? bsum[tid] : 0;
  sh[tid] = v; __syncthreads();
  for (int o = 1; o < 1024; o <<= 1){
    int u = (tid >= o) ? sh[tid - o] : 0;
    __syncthreads();
    sh[tid] += u;
    __syncthreads();
  }
  if (tid < nb) bsum[tid] = sh[tid] - v;   // exclusive
}
__global__ __launch_bounds__(1024) void k_scan3(const int* __restrict__ cnt, int n,
                                                int* __restrict__ offs,
                                                const int* __restrict__ bsum,
                                                int* __restrict__ cursor){
  int i = blockIdx.x * 1024 + threadIdx.x;
  if (i < n){
    int incl = offs[i + 1] + bsum[i >> 10];
    offs[i + 1] = incl;
    cursor[i] = incl - cnt[i];
    if (i == 0) offs[0] = 0;
  }
}

// ---------------- scatB: per-partition bucket -> final CSR slot ----------------
__global__ __launch_bounds__(256) void k_scatb(const u64* __restrict__ buckets, int capp,
                                               const int* __restrict__ gcur,
                                               int* __restrict__ cursor,
                                               int* __restrict__ edges){
  const int p  = blockIdx.x & (NPART - 1);   // partition == XCD (round-robin dispatch)
  const int bb = blockIdx.x >> 3;
  const int n  = gcur[p];
  const u64* bk = buckets + (size_t)p * capp;
  for (int i = bb * 256 + (int)threadIdx.x; i < n; i += SCATB_BPP * 256){
    u64 e = __builtin_nontemporal_load(&bk[i]);
    int seg = (int)(e >> 32);
    int src = (int)(e & 0xffffffffu);
    int pos = atomicAdd(&cursor[seg], 1);
    edges[pos] = src;
  }
}

// ---------------- per-dst-segment softmax + weighted aggregation ----------------
// edges hold absolute src; es/Z indexed by (src - zbase).
template<int NWAVES, int MODE>
__global__ __launch_bounds__(NWAVES * 64) void k_agg(
    const int* __restrict__ offs, int segbase,
    const int* __restrict__ edges, const float* __restrict__ esp,
    const __hip_bfloat16* __restrict__ Z, int zbase,
    const float* __restrict__ emb, float* __restrict__ out,
    const float* __restrict__ efk_buf,
    const float* __restrict__ attn0, const float* __restrict__ b0p,
    const float* __restrict__ attn1, const float* __restrict__ b1p)
{
  constexpr int NT = NWAVES * 64;
  constexpr int NSLOT = NWAVES * 4;
  __shared__ float sred[NWAVES];
  __shared__ float lacc[NWAVES][KD];
  const int tid = threadIdx.x;
  const int wave = tid >> 6, lane = tid & 63;
  const int sub = lane >> 4, li = lane & 15;
  const int seg = segbase + blockIdx.x;
  const int beg = offs[seg], end = offs[seg + 1];

  float m = -3.0e38f;
  for (int i = beg + tid; i < end; i += NT) m = fmaxf(m, esp[edges[i] - zbase]);
  m = wred_max(m);
  if (lane == 0) sred[wave] = m;
  __syncthreads();
  float mm = sred[0];
#pragma unroll
  for (int i = 1; i < NWAVES; ++i) mm = fmaxf(mm, sred[i]);
  __syncthreads();

  float ds = 0.f;
  for (int i = beg + tid; i < end; i += NT) ds += __expf(esp[edges[i] - zbase] - mm);
  ds = wred_sum(ds);
  if (lane == 0) sred[wave] = ds;
  __syncthreads();
  float dsum = 0.f;
#pragma unroll
  for (int i = 0; i < NWAVES; ++i) dsum += sred[i];
  float rden = (end > beg) ? 1.f / dsum : 0.f;

  float acc[8];
#pragma unroll
  for (int j = 0; j < 8; ++j) acc[j] = 0.f;
  const int slot = wave * 4 + sub;
  for (int i = beg + slot; i < end; i += NSLOT){
    int r = edges[i] - zbase;
    float w = __expf(esp[r] - mm);
    bf16x8 z = *(const bf16x8*)(Z + (size_t)r * KD + li * 8);
#pragma unroll
    for (int j = 0; j < 8; ++j) acc[j] = fmaf(w, bf2f(z[j]), acc[j]);
  }
#pragma unroll
  for (int j = 0; j < 8; ++j){
    acc[j] += __shfl_xor(acc[j], 16, 64);
    acc[j] += __shfl_xor(acc[j], 32, 64);
  }
  __syncthreads();
  if (sub == 0){
    f32x4 v0, v1;
#pragma unroll
    for (int j = 0; j < 4; ++j){ v0[j] = acc[j]; v1[j] = acc[4 + j]; }
    *(f32x4*)&lacc[wave][li * 8]     = v0;
    *(f32x4*)&lacc[wave][li * 8 + 4] = v1;
  }
  __syncthreads();

  float accw = 0.f, ex = 0.f, ek = 0.f;
  if (tid < KD){
    float a = 0.f;
#pragma unroll
    for (int wv = 0; wv < NWAVES; ++wv) a += lacc[wv][tid];
    accw = a * rden;
    if (MODE == 1) ex = emb[(size_t)blockIdx.x * KD + tid];
    if (MODE == 2){
      ex = emb[(size_t)blockIdx.x * KD + tid];
      ek = efk_buf[(size_t)blockIdx.x * KD + tid];
    }
  }

  if (MODE == 0){
    if (tid < KD) out[(size_t)blockIdx.x * KD + tid] = accw;
  } else if (MODE == 1){
    if (tid < KD) out[(size_t)blockIdx.x * KD + tid] = ex + accw;
  } else {
    float q0 = 0.f, q1 = 0.f;
    if (tid < KD){
      q0 = ex * attn0[tid] + accw * attn0[KD + tid];
      q1 = ex * attn1[tid] + ek * attn1[KD + tid];
    }
    q0 = wred_sum(q0); q1 = wred_sum(q1);
    if (lane == 0) sred[wave] = q0;
    __syncthreads();
    float s0 = 0.f;
#pragma unroll
    for (int i = 0; i < NWAVES; ++i) s0 += sred[i];
    __syncthreads();
    if (lane == 0) sred[wave] = q1;
    __syncthreads();
    float s1 = 0.f;
#pragma unroll
    for (int i = 0; i < NWAVES; ++i) s1 += sred[i];
    float sc0 = s0 + b0p[0], sc1 = s1 + b1p[0];
    float mx = fmaxf(sc0, sc1);
    float w0 = __expf(sc0 - mx), w1 = __expf(sc1 - mx);
    float inv = 1.f / (w0 + w1);
    w0 *= inv; w1 *= inv;
    if (tid < KD) out[(size_t)blockIdx.x * KD + tid] = ex + w0 * accw + w1 * ek;
  }
}

extern "C" void kernel_launch(void* const* d_in, const int* in_sizes, int n_in,
                              void* d_out, int out_size, void* d_ws, size_t ws_size,
                              hipStream_t stream){
  const int S  = in_sizes[0] / KD;     // 40000
  const int E  = in_sizes[1] / KD;     // 18000
  const int KN = in_sizes[2] / KD;     // 128
  const int nse = in_sizes[19];        // 1.5M
  const int nek = in_sizes[23];        // 180K

  const float* stu  = (const float*)d_in[0];
  const float* exer = (const float*)d_in[1];
  const float* kn   = (const float*)d_in[2];
  const float* sfe_fcW = (const float*)d_in[3];  const float* sfe_attn = (const float*)d_in[4];
  const float* efs_fcW = (const float*)d_in[5];  const float* efs_attn = (const float*)d_in[6];
  const float* efk_fcW = (const float*)d_in[7];  const float* efk_attn = (const float*)d_in[8];
  const float* kfe_fcW = (const float*)d_in[9];  const float* kfe_attn = (const float*)d_in[10];
  const float* ea0W = (const float*)d_in[13]; const float* ea0b = (const float*)d_in[14];
  const float* ea1W = (const float*)d_in[15]; const float* ea1b = (const float*)d_in[16];
  const int* sfe_src = (const int*)d_in[19]; const int* sfe_dst = (const int*)d_in[20];
  const int* efs_src = (const int*)d_in[21]; const int* efs_dst = (const int*)d_in[22];
  const int* efk_src = (const int*)d_in[23]; const int* efk_dst = (const int*)d_in[24];
  const int* kfe_src = (const int*)d_in[25]; const int* kfe_dst = (const int*)d_in[26];
  float* out = (float*)d_out;

  // ---- workspace carve-up ----
  char* w = (char*)d_ws;
  auto alloc = [&](size_t bytes) -> char* {
    char* p = w; w += (bytes + 255) & ~(size_t)255; return p;
  };
  short* Wb               = (short*)alloc((size_t)4 * 16384 * 2);
  __hip_bfloat16* z_sfe   = (__hip_bfloat16*)alloc((size_t)E  * KD * 2);
  __hip_bfloat16* z_efs   = (__hip_bfloat16*)alloc((size_t)S  * KD * 2);
  __hip_bfloat16* z_efk   = (__hip_bfloat16*)alloc((size_t)KN * KD * 2);
  __hip_bfloat16* z_kfe   = (__hip_bfloat16*)alloc((size_t)E  * KD * 2);
  float* es_sfe = (float*)alloc((size_t)E  * 4);
  float* es_efs = (float*)alloc((size_t)S  * 4);
  float* es_efk = (float*)alloc((size_t)KN * 4);
  float* es_kfe = (float*)alloc((size_t)E  * 4);
  float* efk_buf = (float*)alloc((size_t)E * KD * 4);
  const int NSEG = S + E + E + KN;     // 76128
  const size_t TOTE = 2 * (size_t)nse + 2 * (size_t)nek;
  const int CAPP = (int)(TOTE / NPART) + 65536;
  int* cnt8   = (int*)alloc((size_t)NPART * NSEG * 4);
  int* gcur   = (int*)alloc(NPART * 4);
  int* cnt    = (int*)alloc((size_t)NSEG * 4);
  int* offs   = (int*)alloc((size_t)(NSEG + 1) * 4);
  int* cursor = (int*)alloc((size_t)NSEG * 4);
  int* bsum   = (int*)alloc(1024 * 4);
  u64* buckets = (u64*)alloc((size_t)NPART * CAPP * 8);
  int* edges  = (int*)alloc(TOTE * 4);

  hipMemsetAsync(cnt8, 0, (size_t)NPART * NSEG * 4, stream);
  hipMemsetAsync(gcur, 0, NPART * 4, stream);

  // static edge-balanced partition bounds (dsts are uniform within each graph)
  PB pbh;
  {
    long   Cb[5]   = {0, nse, 2L*nse, 2L*nse + nek, 2L*nse + 2L*nek};
    int    base[4] = {0, S, S + E, S + 2*E};
    int    scnt[4] = {S, E, E, KN};
    long   ecnt[4] = {nse, nse, nek, nek};
    pbh.v[0] = 0; pbh.v[8] = NSEG;
    for (int p = 1; p < NPART; ++p){
      long T = ((long)TOTE * p) / NPART;
      int r = 0;
      while (r < 3 && T >= Cb[r + 1]) ++r;
      long off = (long)((double)(T - Cb[r]) * (double)scnt[r] / (double)ecnt[r]);
      if (off >= scnt[r]) off = scnt[r] - 1;
      pbh.v[p] = base[r] + (int)off;
    }
  }

  k_cvt_w<<<256, 256, 0, stream>>>(sfe_fcW, efs_fcW, efk_fcW, kfe_fcW, Wb);

  // mega1: bin+hist (256 blocks) + 4 gemm jobs
  const int nbE = (E + 63) / 64, nbS = (S + 63) / 64, nbK = (KN + 63) / 64;
  Mega1Args ma;
  ma.d0 = sfe_dst; ma.s0 = sfe_src; ma.d1 = efs_dst; ma.s1 = efs_src;
  ma.d2 = efk_dst; ma.s2 = efk_src; ma.d3 = kfe_dst; ma.s3 = kfe_src;
  ma.nse = nse; ma.nek = nek; ma.rebase23 = S + E; ma.nseg = NSEG;
  ma.cnt8 = cnt8; ma.buckets = buckets; ma.capp = CAPP; ma.gcur = gcur; ma.pb = pbh;
  ma.A0 = exer; ma.nA = E; ma.Wb = Wb;
  ma.j[0] = { stu, sfe_attn, z_sfe, es_sfe, S, E,  0,                 0 };
  ma.j[1] = { stu, efs_attn, z_efs, es_efs, 0, S,  nbE,               16384 };
  ma.j[2] = { kn,  efk_attn, z_efk, es_efk, E, KN, nbE + nbS,         32768 };
  ma.j[3] = { kn,  kfe_attn, z_kfe, es_kfe, 0, E,  nbE + nbS + nbK,   49152 };
  const int NBG = nbE + nbS + nbK + nbE;
  k_mega1<<<NBB + NBG, 256, 0, stream>>>(ma);

  int nb = (NSEG + 1023) / 1024;
  k_scan1<<<nb, 1024, 0, stream>>>(cnt8, cnt, NSEG, offs, bsum);
  k_scan2<<<1, 1024, 0, stream>>>(bsum, nb);
  k_scan3<<<nb, 1024, 0, stream>>>(cnt, NSEG, offs, bsum, cursor);

  k_scatb<<<NPART * SCATB_BPP, 256, 0, stream>>>(buckets, CAPP, gcur, cursor, edges);

  // aggregations (efk first: its buffer feeds the exercise combine)
  k_agg<2, 0><<<E, 128, 0, stream>>>(offs, S + E,     edges, es_efk, z_efk, E, nullptr, efk_buf,
                                     nullptr, nullptr, nullptr, nullptr, nullptr);
  k_agg<4, 1><<<S, 256, 0, stream>>>(offs, 0,         edges, es_sfe, z_sfe, S, stu, out,
                                     nullptr, nullptr, nullptr, nullptr, nullptr);
  k_agg<16, 1><<<KN, 1024, 0, stream>>>(offs, S + 2 * E, edges, es_kfe, z_kfe, 0, kn,
                                        out + (size_t)(S + E) * KD,
                                        nullptr, nullptr, nullptr, nullptr, nullptr);
  k_agg<4, 2><<<E, 256, 0, stream>>>(offs, S,         edges, es_efs, z_efs, 0, exer,
                                     out + (size_t)S * KD,
                                     efk_buf, ea0W, ea0b, ea1W, ea1b);
}